// Round 13
// baseline (118.506 us; speedup 1.0000x reference)
//
#include <hip/hip_runtime.h>

// R13: MEASUREMENT ROUND. R11 structure with an in-kernel x4 rep loop so the
// dispatch (~80+ us) outranks the ~58 us poison-fills and finally exposes
// FETCH/WRITE/VALUBusy/Occupancy for OUR kernel. Output identical each pass
// (idempotent); asm memory clobber prevents cross-pass store elimination.
// Per-pass cost = counters / 4.

#define BATCH  4096
#define NCTRL  64
#define SDIM   2048
#define BLK    256               // 4 waves per block
#define WSZ    64
#define NWAVE  (BLK / WSZ)
#define VPT    4                 // consecutive samples per lane
#define CHUNK  (WSZ * VPT)       // 256 samples per wave
#define NXCD   8
#define REP    4

__global__ __launch_bounds__(BLK, 8) void curve_eval_kernel(
    const float4* __restrict__ cp,     // [B, NCTRL] as float4 (x,y,z,w)
    const int*    __restrict__ span,   // [SDIM]
    const float4* __restrict__ basis,  // [SDIM] as float4
    float4*       __restrict__ out)    // [B,SDIM,3] f32 viewed as float4
{
    __shared__ float4 cp_s[NCTRL + 1];                    // 1 KB + pad
    __shared__ float4 out_s4[NWAVE * CHUNK * 3 / 4];      // 12 KB, per-wave regions

    const int wg   = blockIdx.x;
    const int x    = wg & (NXCD - 1);
    const int i    = wg >> 3;                    // 0..1023 per XCD
    const int b    = x * (BATCH / NXCD) + (i >> 1);
    const int s0b  = (i & 1) * (NWAVE * CHUNK);  // 0 or 1024
    const int tid  = threadIdx.x;                // 0..255
    const int wid  = tid >> 6;                   // wave 0..3
    const int lane = tid & (WSZ - 1);            // 0..63

    for (int rep = 0; rep < REP; ++rep) {
        if (tid < NCTRL) {
            const float4 cpv = cp[(size_t)b * NCTRL + tid];
            cp_s[tid] = cpv;
            if (tid == NCTRL - 1) cp_s[NCTRL] = cpv;      // pad
        }
        __syncthreads();

        const int s0    = s0b + wid * CHUNK;
        const int sbase = s0 + lane * VPT;
        const int4 sp4  = reinterpret_cast<const int4*>(span)[(s0 >> 2) + lane];
        const int  sp0  = sp4.x;
        const int  spk[VPT] = {sp4.x, sp4.y, sp4.z, sp4.w};

        float4 rows[5];
        #pragma unroll
        for (int j = 0; j < 5; ++j) rows[j] = cp_s[sp0 - 3 + j];

        float o[VPT * 3];
        #pragma unroll
        for (int k = 0; k < VPT; ++k) {
            const float4 bas = basis[sbase + k];
            const bool hi = (spk[k] > sp0);
            const float w0 = hi ? 0.0f  : bas.x;
            const float w1 = hi ? bas.x : bas.y;
            const float w2 = hi ? bas.y : bas.z;
            const float w3 = hi ? bas.z : bas.w;
            const float w4 = hi ? bas.w : 0.0f;

            const float xx = w0*rows[0].x + w1*rows[1].x + w2*rows[2].x + w3*rows[3].x + w4*rows[4].x;
            const float yy = w0*rows[0].y + w1*rows[1].y + w2*rows[2].y + w3*rows[3].y + w4*rows[4].y;
            const float zz = w0*rows[0].z + w1*rows[1].z + w2*rows[2].z + w3*rows[3].z + w4*rows[4].z;
            const float ww = w0*rows[0].w + w1*rows[1].w + w2*rows[2].w + w3*rows[3].w + w4*rows[4].w;

            const float invw = __builtin_amdgcn_rcpf(ww);
            o[k * 3 + 0] = xx * invw;
            o[k * 3 + 1] = yy * invw;
            o[k * 3 + 2] = zz * invw;
        }

        float4* region = &out_s4[wid * (CHUNK * 3 / 4)];
        float4* mine   = &region[lane * 3];
        mine[0] = make_float4(o[0], o[1],  o[2],  o[3]);
        mine[1] = make_float4(o[4], o[5],  o[6],  o[7]);
        mine[2] = make_float4(o[8], o[9],  o[10], o[11]);

        asm volatile("s_waitcnt lgkmcnt(0)" ::: "memory");

        const size_t base4 = ((size_t)b * SDIM + (size_t)s0) * 3u / 4u;
        #pragma unroll
        for (int k = 0; k < 3; ++k) {
            out[base4 + lane + k * WSZ] = region[lane + k * WSZ];
        }

        __syncthreads();                       // re-converge before next pass
        asm volatile("" ::: "memory");         // forbid cross-pass store DSE
    }
}

extern "C" void kernel_launch(void* const* d_in, const int* in_sizes, int n_in,
                              void* d_out, int out_size, void* d_ws, size_t ws_size,
                              hipStream_t stream) {
    const float4* cp    = (const float4*)d_in[0];  // [4096,64,4] f32
    const int*    span  = (const int*)d_in[1];     // [2048] i32
    const float4* basis = (const float4*)d_in[2];  // [2048,4] f32
    float4*       out   = (float4*)d_out;          // [4096,2048,3] f32

    const int nblocks = BATCH * SDIM / (NWAVE * CHUNK);   // 8192 4-wave blocks
    curve_eval_kernel<<<nblocks, BLK, 0, stream>>>(cp, span, basis, out);
}

// Round 15
// 62.220 us; speedup vs baseline: 1.9046x; 1.9046x over previous
//
#include <hip/hip_runtime.h>

#define BATCH  4096
#define NCTRL  64
#define SDIM   2048
#define BLK    256               // 4 waves per block
#define WSZ    64
#define NWAVE  (BLK / WSZ)
#define VPT    4                 // consecutive samples per lane
#define CHUNK  (WSZ * VPT)       // 256 samples per wave; block covers 1024
#define NXCD   8
#define GRP    4                 // curves per block: basis/span read ONCE for 4 curves

__global__ __launch_bounds__(BLK, 8) void curve_eval_kernel(
    const float4* __restrict__ cp,     // [B, NCTRL] as float4 (x,y,z,w)
    const int*    __restrict__ span,   // [SDIM]
    const float4* __restrict__ basis,  // [SDIM] as float4
    float4*       __restrict__ out)    // [B,SDIM,3] f32 viewed as float4
{
    __shared__ float4 cp_s[GRP][NCTRL + 1];               // 4x(1KB+pad) = 4.2KB
    __shared__ float4 out_s4[NWAVE][CHUNK * 3 / 4];       // 12KB, per-wave 3KB regions

    // Decode (2048 blocks total = 8 XCD x 256):
    //   x = XCD (round-robin on raw wg), i = 0..255 per XCD,
    //   c = i & 1  -> which 1024-sample half of the curves,
    //   g = i >> 1 -> curve group 0..127 within this XCD's 512-curve slab.
    const int wg   = blockIdx.x;
    const int x    = wg & (NXCD - 1);
    const int i    = wg >> 3;                    // 0..255 per XCD
    const int c    = i & 1;                      // sample half (x1024)
    const int g    = i >> 1;                     // curve group 0..127
    const int b0   = x * (BATCH / NXCD) + g * GRP;
    const int tid  = threadIdx.x;                // 0..255
    const int wid  = tid >> 6;                   // wave 0..3
    const int lane = tid & (WSZ - 1);            // 0..63

    // Stage cp for 4 curves in ONE parallel burst: wave w loads curve w
    // (64 lanes x 16B contiguous = 1KB), one ds_write_b128 each.
    {
        const float4 cpv = cp[(size_t)(b0 + wid) * NCTRL + lane];
        cp_s[wid][lane] = cpv;
        if (lane == NCTRL - 1) cp_s[wid][NCTRL] = cpv;    // pad row (weight unused)
    }
    __syncthreads();   // only block-wide barrier

    // Wave w owns samples [c*1024 + w*256, +256) — same range for all 4 curves.
    // Basis/span loaded ONCE into registers, reused across the 4 curves.
    const int s0    = c * (NWAVE * CHUNK) + wid * CHUNK;   // <= 1792
    const int sbase = s0 + lane * VPT;
    const int4 sp4  = reinterpret_cast<const int4*>(span)[(s0 >> 2) + lane];
    const int  sp0  = sp4.x;
    const int  spk[VPT] = {sp4.x, sp4.y, sp4.z, sp4.w};

    float4 bas[VPT];
    #pragma unroll
    for (int k = 0; k < VPT; ++k) bas[k] = basis[sbase + k];

    // Pre-shift the 4 basis vectors into 5-wide window weights (curve-indep).
    float wgt[VPT][5];
    #pragma unroll
    for (int k = 0; k < VPT; ++k) {
        const bool hi = (spk[k] > sp0);
        wgt[k][0] = hi ? 0.0f     : bas[k].x;
        wgt[k][1] = hi ? bas[k].x : bas[k].y;
        wgt[k][2] = hi ? bas[k].y : bas[k].z;
        wgt[k][3] = hi ? bas[k].z : bas[k].w;
        wgt[k][4] = hi ? bas[k].w : 0.0f;
    }

    float4* region = &out_s4[wid][0];
    float4* mine   = &region[lane * 3];

    #pragma unroll
    for (int cv = 0; cv < GRP; ++cv) {
        // One 5-row window serves the lane's 4 consecutive samples.
        float4 rows[5];
        #pragma unroll
        for (int j = 0; j < 5; ++j) rows[j] = cp_s[cv][sp0 - 3 + j];

        float o[VPT * 3];
        #pragma unroll
        for (int k = 0; k < VPT; ++k) {
            const float xx = wgt[k][0]*rows[0].x + wgt[k][1]*rows[1].x + wgt[k][2]*rows[2].x + wgt[k][3]*rows[3].x + wgt[k][4]*rows[4].x;
            const float yy = wgt[k][0]*rows[0].y + wgt[k][1]*rows[1].y + wgt[k][2]*rows[2].y + wgt[k][3]*rows[3].y + wgt[k][4]*rows[4].y;
            const float zz = wgt[k][0]*rows[0].z + wgt[k][1]*rows[1].z + wgt[k][2]*rows[2].z + wgt[k][3]*rows[3].z + wgt[k][4]*rows[4].z;
            const float ww = wgt[k][0]*rows[0].w + wgt[k][1]*rows[1].w + wgt[k][2]*rows[2].w + wgt[k][3]*rows[3].w + wgt[k][4]*rows[4].w;

            const float invw = __builtin_amdgcn_rcpf(ww);  // 5x headroom vs threshold
            o[k * 3 + 0] = xx * invw;
            o[k * 3 + 1] = yy * invw;
            o[k * 3 + 2] = zz * invw;
        }

        // Wave-local transpose through this wave's private 3KB LDS region.
        // DS ops are in-order per wave; next curve's ds_writes cannot pass
        // this curve's ds_reads. No block barrier between curves.
        mine[0] = make_float4(o[0], o[1],  o[2],  o[3]);
        mine[1] = make_float4(o[4], o[5],  o[6],  o[7]);
        mine[2] = make_float4(o[8], o[9],  o[10], o[11]);
        asm volatile("s_waitcnt lgkmcnt(0)" ::: "memory");

        // Coalesced flush: 3 instrs x 1KB contiguous per wave.
        const size_t base4 = ((size_t)(b0 + cv) * SDIM + (size_t)s0) * 3u / 4u;
        #pragma unroll
        for (int k = 0; k < 3; ++k) {
            out[base4 + lane + k * WSZ] = region[lane + k * WSZ];
        }
    }
}

extern "C" void kernel_launch(void* const* d_in, const int* in_sizes, int n_in,
                              void* d_out, int out_size, void* d_ws, size_t ws_size,
                              hipStream_t stream) {
    const float4* cp    = (const float4*)d_in[0];  // [4096,64,4] f32
    const int*    span  = (const int*)d_in[1];     // [2048] i32
    const float4* basis = (const float4*)d_in[2];  // [2048,4] f32
    float4*       out   = (float4*)d_out;          // [4096,2048,3] f32

    const int nblocks = BATCH * SDIM / (NWAVE * CHUNK * GRP);  // 2048 blocks
    curve_eval_kernel<<<nblocks, BLK, 0, stream>>>(cp, span, basis, out);
}

// Round 16
// 26.842 us; speedup vs baseline: 4.4150x; 2.3180x over previous
//
#include <hip/hip_runtime.h>

#define BATCH  4096
#define NCTRL  64
#define SDIM   2048
#define BLK    256               // 4 waves per block
#define WSZ    64
#define NWAVE  (BLK / WSZ)
#define VPT    4                 // consecutive samples per lane
#define CHUNK  (WSZ * VPT)       // 256 samples per chunk
#define NCHNK  2                 // chunks per wave -> block = 1 whole curve
#define NXCD   8

__global__ __launch_bounds__(BLK, 8) void curve_eval_kernel(
    const float4* __restrict__ cp,     // [B, NCTRL] as float4 (x,y,z,w)
    const int*    __restrict__ span,   // [SDIM]
    const float4* __restrict__ basis,  // [SDIM] as float4
    float4*       __restrict__ out)    // [B,SDIM,3] f32 viewed as float4
{
    __shared__ float4 cp_s[NCTRL + 1];                    // 1 KB + pad
    __shared__ float4 out_s4[NWAVE][CHUNK * 3 / 4];       // 12 KB, per-wave 3KB

    // One block = one curve. XCD slab mapping as in R11: x = wg&7,
    // b = x*512 + (wg>>3); each XCD owns a contiguous 512-curve slab.
    const int wg   = blockIdx.x;
    const int x    = wg & (NXCD - 1);
    const int g    = wg >> 3;                    // 0..511 per XCD
    const int b    = x * (BATCH / NXCD) + g;
    const int tid  = threadIdx.x;                // 0..255
    const int wid  = tid >> 6;                   // wave 0..3
    const int lane = tid & (WSZ - 1);            // 0..63

    if (tid < NCTRL) {
        const float4 cpv = cp[(size_t)b * NCTRL + tid];
        cp_s[tid] = cpv;
        if (tid == NCTRL - 1) cp_s[NCTRL] = cpv;          // pad (weight unused)
    }
    __syncthreads();   // only block-wide barrier; waves decouple after this

    float4* region = &out_s4[wid][0];
    float4* mine   = &region[lane * 3];

    // Wave w owns 512 consecutive samples [w*512, w*512+512), processed as
    // 2 chunks of 256 -> 6 global store instrs per wave (vs 3 in R11),
    // prologue amortized 2x, occupancy unchanged (32 waves/CU).
    #pragma unroll
    for (int j = 0; j < NCHNK; ++j) {
        const int s0    = wid * (NCHNK * CHUNK) + j * CHUNK;   // <= 1792
        const int sbase = s0 + lane * VPT;
        const int4 sp4  = reinterpret_cast<const int4*>(span)[(s0 >> 2) + lane];
        const int  sp0  = sp4.x;
        const int  spk[VPT] = {sp4.x, sp4.y, sp4.z, sp4.w};

        // One 5-row window serves the lane's 4 consecutive samples.
        float4 rows[5];
        #pragma unroll
        for (int jj = 0; jj < 5; ++jj) rows[jj] = cp_s[sp0 - 3 + jj];

        float o[VPT * 3];
        #pragma unroll
        for (int k = 0; k < VPT; ++k) {
            const float4 bas = basis[sbase + k];   // L1-resident (32 KB total)
            const bool hi = (spk[k] > sp0);        // shift basis one row down
            const float w0 = hi ? 0.0f  : bas.x;
            const float w1 = hi ? bas.x : bas.y;
            const float w2 = hi ? bas.y : bas.z;
            const float w3 = hi ? bas.z : bas.w;
            const float w4 = hi ? bas.w : 0.0f;

            const float xx = w0*rows[0].x + w1*rows[1].x + w2*rows[2].x + w3*rows[3].x + w4*rows[4].x;
            const float yy = w0*rows[0].y + w1*rows[1].y + w2*rows[2].y + w3*rows[3].y + w4*rows[4].y;
            const float zz = w0*rows[0].z + w1*rows[1].z + w2*rows[2].z + w3*rows[3].z + w4*rows[4].z;
            const float ww = w0*rows[0].w + w1*rows[1].w + w2*rows[2].w + w3*rows[3].w + w4*rows[4].w;

            const float invw = __builtin_amdgcn_rcpf(ww);  // 5x headroom vs thr
            o[k * 3 + 0] = xx * invw;
            o[k * 3 + 1] = yy * invw;
            o[k * 3 + 2] = zz * invw;
        }

        // Wave-local transpose via this wave's private 3KB LDS region.
        // DS is in-order per wave; lgkmcnt(0) makes all lanes' writes visible.
        mine[0] = make_float4(o[0], o[1],  o[2],  o[3]);
        mine[1] = make_float4(o[4], o[5],  o[6],  o[7]);
        mine[2] = make_float4(o[8], o[9],  o[10], o[11]);
        asm volatile("s_waitcnt lgkmcnt(0)" ::: "memory");

        // Coalesced flush: 3 instrs x (64 lanes x 16B) = 3 KB contiguous.
        const size_t base4 = ((size_t)b * SDIM + (size_t)s0) * 3u / 4u;
        #pragma unroll
        for (int k = 0; k < 3; ++k) {
            out[base4 + lane + k * WSZ] = region[lane + k * WSZ];
        }
    }
}

extern "C" void kernel_launch(void* const* d_in, const int* in_sizes, int n_in,
                              void* d_out, int out_size, void* d_ws, size_t ws_size,
                              hipStream_t stream) {
    const float4* cp    = (const float4*)d_in[0];  // [4096,64,4] f32
    const int*    span  = (const int*)d_in[1];     // [2048] i32
    const float4* basis = (const float4*)d_in[2];  // [2048,4] f32
    float4*       out   = (float4*)d_out;          // [4096,2048,3] f32

    curve_eval_kernel<<<BATCH, BLK, 0, stream>>>(cp, span, basis, out);
}

// Round 17
// 24.330 us; speedup vs baseline: 4.8708x; 1.1032x over previous
//
#include <hip/hip_runtime.h>

#define BATCH  4096
#define NCTRL  64
#define SDIM   2048
#define BLK    256               // 4 waves per block
#define WSZ    64
#define NWAVE  (BLK / WSZ)
#define VPT    4                 // consecutive samples per lane
#define CHUNK  (WSZ * VPT)       // 256 samples per wave
#define NXCD   8

__global__ __launch_bounds__(BLK, 8) void curve_eval_kernel(
    const float4* __restrict__ cp,     // [B, NCTRL] as float4 (x,y,z,w)
    const int*    __restrict__ span,   // [SDIM]
    const float4* __restrict__ basis,  // [SDIM] as float4
    float4*       __restrict__ out)    // [B,SDIM,3] f32 viewed as float4
{
    __shared__ float4 cp_s[NCTRL + 1];                    // 1 KB + pad
    __shared__ float4 out_s4[NWAVE * CHUNK * 3 / 4];      // 12 KB, per-wave regions

    // R11 structure; ONE change: sample-half c varies SLOWEST across the
    // dispatch (was fastest). All concurrently-resident blocks machine-wide
    // then share the same 1024-sample half -> per-CU live basis+span set
    // ~18 KB -> L1-resident -> basis/span HBM re-fetch (~27 MB) vanishes.
    const int wg   = blockIdx.x;
    const int x    = wg & (NXCD - 1);
    const int i    = wg >> 3;                    // 0..1023 per XCD
    const int c    = i >> 9;                     // sample half: SLOWEST (0 then 1)
    const int g    = i & 511;                    // curve 0..511 within XCD slab
    const int b    = x * (BATCH / NXCD) + g;
    const int s0b  = c * (NWAVE * CHUNK);        // 0 or 1024
    const int tid  = threadIdx.x;                // 0..255
    const int wid  = tid >> 6;                   // wave 0..3
    const int lane = tid & (WSZ - 1);            // 0..63

    if (tid < NCTRL) {
        const float4 cpv = cp[(size_t)b * NCTRL + tid];
        cp_s[tid] = cpv;
        if (tid == NCTRL - 1) cp_s[NCTRL] = cpv;          // pad (weight unused)
    }
    __syncthreads();   // only block-wide barrier; waves decouple after this

    const int s0    = s0b + wid * CHUNK;
    const int sbase = s0 + lane * VPT;
    const int4 sp4  = reinterpret_cast<const int4*>(span)[(s0 >> 2) + lane];
    const int  sp0  = sp4.x;
    const int  spk[VPT] = {sp4.x, sp4.y, sp4.z, sp4.w};

    float4 rows[5];
    #pragma unroll
    for (int j = 0; j < 5; ++j) rows[j] = cp_s[sp0 - 3 + j];

    float o[VPT * 3];
    #pragma unroll
    for (int k = 0; k < VPT; ++k) {
        const float4 bas = basis[sbase + k];
        const bool hi = (spk[k] > sp0);
        const float w0 = hi ? 0.0f  : bas.x;
        const float w1 = hi ? bas.x : bas.y;
        const float w2 = hi ? bas.y : bas.z;
        const float w3 = hi ? bas.z : bas.w;
        const float w4 = hi ? bas.w : 0.0f;

        const float xx = w0*rows[0].x + w1*rows[1].x + w2*rows[2].x + w3*rows[3].x + w4*rows[4].x;
        const float yy = w0*rows[0].y + w1*rows[1].y + w2*rows[2].y + w3*rows[3].y + w4*rows[4].y;
        const float zz = w0*rows[0].z + w1*rows[1].z + w2*rows[2].z + w3*rows[3].z + w4*rows[4].z;
        const float ww = w0*rows[0].w + w1*rows[1].w + w2*rows[2].w + w3*rows[3].w + w4*rows[4].w;

        const float invw = __builtin_amdgcn_rcpf(ww);     // 5x headroom vs threshold
        o[k * 3 + 0] = xx * invw;
        o[k * 3 + 1] = yy * invw;
        o[k * 3 + 2] = zz * invw;
    }

    // Wave-local transpose through this wave's private 3KB LDS region.
    float4* region = &out_s4[wid * (CHUNK * 3 / 4)];
    float4* mine   = &region[lane * 3];
    mine[0] = make_float4(o[0], o[1],  o[2],  o[3]);
    mine[1] = make_float4(o[4], o[5],  o[6],  o[7]);
    mine[2] = make_float4(o[8], o[9],  o[10], o[11]);

    asm volatile("s_waitcnt lgkmcnt(0)" ::: "memory");

    // Coalesced flush: 3 instrs x (64 lanes x 16B) fully contiguous.
    const size_t base4 = ((size_t)b * SDIM + (size_t)s0) * 3u / 4u;
    #pragma unroll
    for (int k = 0; k < 3; ++k) {
        out[base4 + lane + k * WSZ] = region[lane + k * WSZ];
    }
}

extern "C" void kernel_launch(void* const* d_in, const int* in_sizes, int n_in,
                              void* d_out, int out_size, void* d_ws, size_t ws_size,
                              hipStream_t stream) {
    const float4* cp    = (const float4*)d_in[0];  // [4096,64,4] f32
    const int*    span  = (const int*)d_in[1];     // [2048] i32
    const float4* basis = (const float4*)d_in[2];  // [2048,4] f32
    float4*       out   = (float4*)d_out;          // [4096,2048,3] f32

    const int nblocks = BATCH * SDIM / (NWAVE * CHUNK);   // 8192 4-wave blocks
    curve_eval_kernel<<<nblocks, BLK, 0, stream>>>(cp, span, basis, out);
}